// Round 8
// baseline (50297.028 us; speedup 1.0000x reference)
//
#include <hip/hip_runtime.h>

// Persistent-LSTM MI355X — Round 8: R6 protocol + single-barrier producer.
// R7 lesson: compact-tag detect NEEDS data-before-tag ordering (concurrent
// hint -> pair-validation storms, FETCH 2GB, +12ms). R6 (34.4ms) is the best
// protocol; its producer side costs: publish -> syncthreads(all-wave drain)
// -> tid0 tag store = barrier release + serialized drain after slowest wave.
// R8 producer: each wave publishes, does its OWN s_waitcnt vmcnt(0) drain
// (drains overlap wave skew), then LDS monotonic counter fetch_add; the
// 8th-to-arrive wave stores the block tag immediately. One barrier/step
// (the post-stage one). Consumer side identical to R6 (2 tag lines/wave,
// one-shot 1KB data fetch — FETCH_SIZE 0.45GB proved it storm-free).
//
// 256 blocks x 512 threads, 1 block/CU -> all co-resident, spin safe.
// Block b owns units [8b,8b+8); wave wv computes unit j=8b+wv; lane ln owns
// h-chunks {ln+64k} for FMA; staging slice = 4 contiguous floats/lane.
// Tag slots: [256] u32, signed compare (0xAA poison negative -> inert).

#define H      2048
#define TSTEPS 8192
#define FEAT   128
#define NBLK   256
#define NTHR   512

typedef float vf4 __attribute__((ext_vector_type(4)));
typedef float vf2 __attribute__((ext_vector_type(2)));
typedef unsigned long long u64;
typedef unsigned int u32;

__device__ __forceinline__ float sigm(float xv) {
  return __builtin_amdgcn_rcpf(1.0f + __expf(-xv));
}
__device__ __forceinline__ float tanh_(float xv) {
  return 1.0f - 2.0f * __builtin_amdgcn_rcpf(__expf(2.0f * xv) + 1.0f);
}

__device__ __forceinline__ u64 aload64(const u64* p) {
  return __hip_atomic_load(p, __ATOMIC_RELAXED, __HIP_MEMORY_SCOPE_AGENT);
}
__device__ __forceinline__ u32 aload32(const u32* p) {
  return __hip_atomic_load(p, __ATOMIC_RELAXED, __HIP_MEMORY_SCOPE_AGENT);
}
__device__ __forceinline__ void astoref(float* p, float v) {
  __hip_atomic_store(p, v, __ATOMIC_RELAXED, __HIP_MEMORY_SCOPE_AGENT);
}
__device__ __forceinline__ void astoreu(u32* p, u32 v) {
  __hip_atomic_store(p, v, __ATOMIC_RELAXED, __HIP_MEMORY_SCOPE_AGENT);
}

#define DECLG(g) vf4 w##g##_0, w##g##_1, w##g##_2, w##g##_3, \
                     w##g##_4, w##g##_5, w##g##_6, w##g##_7; \
                 vf2 wih##g; float bias##g; float acc##g;

#define LOADG(g) { \
  const int row_ = (g) * H + j; \
  const float* wr_ = W_hh + (long)row_ * H; \
  w##g##_0 = *(const vf4*)(wr_ + 4*(ln      )); \
  w##g##_1 = *(const vf4*)(wr_ + 4*(ln +  64)); \
  w##g##_2 = *(const vf4*)(wr_ + 4*(ln + 128)); \
  w##g##_3 = *(const vf4*)(wr_ + 4*(ln + 192)); \
  w##g##_4 = *(const vf4*)(wr_ + 4*(ln + 256)); \
  w##g##_5 = *(const vf4*)(wr_ + 4*(ln + 320)); \
  w##g##_6 = *(const vf4*)(wr_ + 4*(ln + 384)); \
  w##g##_7 = *(const vf4*)(wr_ + 4*(ln + 448)); \
  wih##g  = *(const vf2*)(W_ih + (long)row_ * FEAT + 2*ln); \
  bias##g = b_ih[row_] + b_hh[row_]; }

// Opaque pin: weights become non-rematerializable (cannot re-sink into loop).
#define PIN(g) asm volatile("" : \
  "+v"(w##g##_0), "+v"(w##g##_1), "+v"(w##g##_2), "+v"(w##g##_3), \
  "+v"(w##g##_4), "+v"(w##g##_5), "+v"(w##g##_6), "+v"(w##g##_7), \
  "+v"(wih##g), "+v"(bias##g));

#define LDSREAD(k, ldsrow) \
  const vf4 hv##k = *(const vf4*)&(ldsrow)[4*(ln + 64*(k))];

#define FMA_G(g, c) \
  acc##g = __builtin_fmaf(w##g##_##c.x, h4_.x, acc##g); \
  acc##g = __builtin_fmaf(w##g##_##c.y, h4_.y, acc##g); \
  acc##g = __builtin_fmaf(w##g##_##c.z, h4_.z, acc##g); \
  acc##g = __builtin_fmaf(w##g##_##c.w, h4_.w, acc##g);

#define FMA_C(c) { const vf4 h4_ = hv##c; \
  FMA_G(0, c) FMA_G(1, c) FMA_G(2, c) FMA_G(3, c) }

#define REDUCE(g) { float a_ = acc##g; \
  a_ += __shfl_xor(a_, 1);  a_ += __shfl_xor(a_, 2);  a_ += __shfl_xor(a_, 4); \
  a_ += __shfl_xor(a_, 8);  a_ += __shfl_xor(a_, 16); a_ += __shfl_xor(a_, 32); \
  acc##g = a_ + bias##g; }

// R6 consumer (proven storm-free): poll this slice's 32 producer-block slots
// (2 cache lines, 1 load/lane on lanes 0..31), then one-shot fetch the 256
// floats (4/lane) and deposit into LDS. Data is guaranteed fresh at detect
// because producers drain h before storing their tag.
__device__ __forceinline__ void poll_and_stage(const u32* __restrict__ slots,
                                               const float* __restrict__ hsrc,
                                               int tgt,
                                               float* __restrict__ ldsrow,
                                               int wv, int ln) {
  const u32* sp = slots + wv * 32 + (ln & 31);
  int v = (int)aload32(sp);
  while (!__all((ln < 32) ? (v >= tgt) : 1)) {
    __builtin_amdgcn_s_sleep(1);
    if ((ln < 32) && (v < tgt)) v = (int)aload32(sp);
  }
  const int base = wv * 256 + 4 * ln;
  const u64* hp = (const u64*)(hsrc + base);
  const u64 d0 = aload64(hp);
  const u64 d1 = aload64(hp + 1);
  vf4 hv;
  hv.x = __uint_as_float((u32)d0);
  hv.y = __uint_as_float((u32)(d0 >> 32));
  hv.z = __uint_as_float((u32)d1);
  hv.w = __uint_as_float((u32)(d1 >> 32));
  *(vf4*)&ldsrow[base] = hv;
}

__global__ __launch_bounds__(NTHR, 2)
void lstm_persist(const float* __restrict__ x,
                  const float* __restrict__ W_ih,
                  const float* __restrict__ W_hh,
                  const float* __restrict__ b_ih,
                  const float* __restrict__ b_hh,
                  const float* __restrict__ W_lin,
                  const float* __restrict__ b_lin,
                  const float* __restrict__ W_out,
                  const float* __restrict__ b_out,
                  float* __restrict__ out,
                  float* __restrict__ ws)
{
  const int tid = threadIdx.x;
  const int b   = blockIdx.x;
  const int wv  = tid >> 6;
  const int ln  = tid & 63;

  float* hbuf0 = ws;            // [2048] h for even t
  float* hbuf1 = ws + H;        // [2048] h for odd t; reused for ylin
  u32*   slots = (u32*)(ws + 2 * H);   // [256] per-block step counters

  __shared__ __align__(16) float h_lds[2][H];
  __shared__ u32 wdone;   // monotonic per-block wave-drain counter

  // h_0 = 0: zero parity-0 LDS row; init drain counter
  *(vf4*)&h_lds[0][4 * tid] = (vf4)(0.0f);
  if (tid == 0) wdone = 0;

  // ---- persistent weights: load then pin ----
  const int j = b * 8 + wv;
  DECLG(0) DECLG(1) DECLG(2) DECLG(3)
  LOADG(0) LOADG(1) LOADG(2) LOADG(3)
  PIN(0) PIN(1) PIN(2) PIN(3)

  __syncthreads();

  float cst = 0.0f;

  #pragma unroll 1
  for (int t = 0; t < TSTEPS; ++t) {
    const vf2 xr = *(const vf2*)(x + (long)t * FEAT + 2 * ln);
    float* ldsrow = h_lds[t & 1];

    if (t > 0)
      poll_and_stage(slots, (t & 1) ? hbuf1 : hbuf0, t, ldsrow, wv, ln);
    __syncthreads();   // the ONLY barrier per step

    LDSREAD(0, ldsrow) LDSREAD(1, ldsrow) LDSREAD(2, ldsrow) LDSREAD(3, ldsrow)
    LDSREAD(4, ldsrow) LDSREAD(5, ldsrow) LDSREAD(6, ldsrow) LDSREAD(7, ldsrow)

    acc0 = wih0.x * xr.x + wih0.y * xr.y;
    acc1 = wih1.x * xr.x + wih1.y * xr.y;
    acc2 = wih2.x * xr.x + wih2.y * xr.y;
    acc3 = wih3.x * xr.x + wih3.y * xr.y;

    FMA_C(0) FMA_C(1) FMA_C(2) FMA_C(3)
    FMA_C(4) FMA_C(5) FMA_C(6) FMA_C(7)

    REDUCE(0) REDUCE(1) REDUCE(2) REDUCE(3)

    // gate order [i, f, g, o]
    const float iv = sigm(acc0);
    const float fv = sigm(acc1);
    const float gv = tanh_(acc2);
    const float ov = sigm(acc3);
    cst = fv * cst + iv * gv;
    const float hval = ov * tanh_(cst);

    // publish h_{t+1} (one sc1 store per wave)
    if (ln == 0)
      astoref((((t + 1) & 1) ? hbuf1 : hbuf0) + j, hval);

    // wave-level drain: this wave's h store is visible at L3 after this.
    asm volatile("s_waitcnt vmcnt(0)" ::: "memory");

    // LDS monotonic aggregation; 8th-to-drain wave stores the block tag.
    if (ln == 0) {
      const u32 old = __hip_atomic_fetch_add(&wdone, 1u, __ATOMIC_RELAXED,
                                             __HIP_MEMORY_SCOPE_WORKGROUP);
      if (old == 8u * (u32)(t + 1) - 1u)
        astoreu(slots + b, (u32)(t + 1));
    }
  }

  // ---- head phase 1: ylin[j] = b_lin[j] + dot(W_lin[j,:], h_final) ----
  // h_final = h_8192 in hbuf0; slots reach TSTEPS when all blocks publish.
  {
    float* ldsrow = h_lds[0];
    poll_and_stage(slots, hbuf0, TSTEPS, ldsrow, wv, ln);
    __syncthreads();

    float a0 = 0.0f;
    const float* wl = W_lin + (long)j * H;
    #pragma unroll
    for (int k = 0; k < 8; ++k) {
      const vf4 h4 = *(const vf4*)&ldsrow[4 * (ln + 64 * k)];
      const vf4 u  = *(const vf4*)(wl + 4 * (ln + 64 * k));
      a0 += u.x * h4.x + u.y * h4.y + u.z * h4.z + u.w * h4.w;
    }
    a0 += __shfl_xor(a0, 1);  a0 += __shfl_xor(a0, 2);  a0 += __shfl_xor(a0, 4);
    a0 += __shfl_xor(a0, 8);  a0 += __shfl_xor(a0, 16); a0 += __shfl_xor(a0, 32);

    if (ln == 0)
      astoref(hbuf1 + j, a0 + b_lin[j]);   // ylin in hbuf1 (all blocks are
                                           // past reading h_8191 by now)
    asm volatile("s_waitcnt vmcnt(0)" ::: "memory");
    if (ln == 0) {
      const u32 old = __hip_atomic_fetch_add(&wdone, 1u, __ATOMIC_RELAXED,
                                             __HIP_MEMORY_SCOPE_WORKGROUP);
      if (old == 8u * (u32)(TSTEPS + 1) - 1u)
        astoreu(slots + b, (u32)(TSTEPS + 1));
    }
  }

  // ---- head phase 2: y = ylin @ W_out.T + b_out (block 0, wave 0) ----
  if (b == 0 && wv == 0) {
    // poll all 256 slots: lane ln covers slots 4ln..4ln+3
    const u32* sp = slots + 4 * ln;
    int v0 = (int)aload32(sp + 0), v1 = (int)aload32(sp + 1);
    int v2 = (int)aload32(sp + 2), v3 = (int)aload32(sp + 3);
    const int tgt = TSTEPS + 1;
    while (!__all((v0 >= tgt) & (v1 >= tgt) & (v2 >= tgt) & (v3 >= tgt))) {
      __builtin_amdgcn_s_sleep(1);
      if (v0 < tgt) v0 = (int)aload32(sp + 0);
      if (v1 < tgt) v1 = (int)aload32(sp + 1);
      if (v2 < tgt) v2 = (int)aload32(sp + 2);
      if (v3 < tgt) v3 = (int)aload32(sp + 3);
    }
    float p0 = 0.0f, p1 = 0.0f;
    #pragma unroll
    for (int k = 0; k < 16; ++k) {
      const u64 d  = aload64((const u64*)hbuf1 + ln + 64 * k);
      const int c  = 2 * (ln + 64 * k);
      const float ylo = __uint_as_float((u32)d);
      const float yhi = __uint_as_float((u32)(d >> 32));
      p0 = __builtin_fmaf(W_out[c],         ylo, p0);
      p0 = __builtin_fmaf(W_out[c + 1],     yhi, p0);
      p1 = __builtin_fmaf(W_out[H + c],     ylo, p1);
      p1 = __builtin_fmaf(W_out[H + c + 1], yhi, p1);
    }
    p0 += __shfl_xor(p0, 1);  p0 += __shfl_xor(p0, 2);  p0 += __shfl_xor(p0, 4);
    p0 += __shfl_xor(p0, 8);  p0 += __shfl_xor(p0, 16); p0 += __shfl_xor(p0, 32);
    p1 += __shfl_xor(p1, 1);  p1 += __shfl_xor(p1, 2);  p1 += __shfl_xor(p1, 4);
    p1 += __shfl_xor(p1, 8);  p1 += __shfl_xor(p1, 16); p1 += __shfl_xor(p1, 32);
    if (ln == 0) {
      out[0] = p0 + b_out[0];
      out[1] = p1 + b_out[1];
    }
  }
}

extern "C" void kernel_launch(void* const* d_in, const int* in_sizes, int n_in,
                              void* d_out, int out_size, void* d_ws, size_t ws_size,
                              hipStream_t stream) {
  const float* x     = (const float*)d_in[0];
  const float* W_ih  = (const float*)d_in[1];
  const float* W_hh  = (const float*)d_in[2];
  const float* b_ih  = (const float*)d_in[3];
  const float* b_hh  = (const float*)d_in[4];
  const float* W_lin = (const float*)d_in[5];
  const float* b_lin = (const float*)d_in[6];
  const float* W_out = (const float*)d_in[7];
  const float* b_out = (const float*)d_in[8];

  lstm_persist<<<dim3(NBLK), dim3(NTHR), 0, stream>>>(
      x, W_ih, W_hh, b_ih, b_hh, W_lin, b_lin, W_out, b_out,
      (float*)d_out, (float*)d_ws);
}